// Round 1
// baseline (13156.529 us; speedup 1.0000x reference)
//
#include <hip/hip_runtime.h>
#include <hip/hip_bf16.h>

#define NN 8192
#define NE 262144
#define DN 128
#define DE 10
#define DM 64
#define HL 256
#define DA 512

typedef __attribute__((ext_vector_type(2))) _Float16 h2_t;
typedef __attribute__((ext_vector_type(8))) short short8;
typedef __attribute__((ext_vector_type(4))) float f32x4;

__device__ __forceinline__ float fast_rcp(float x) {
#if __has_builtin(__builtin_amdgcn_rcpf)
  return __builtin_amdgcn_rcpf(x);
#else
  return 1.0f / x;
#endif
}
__device__ __forceinline__ float sigf(float x) {
  return fast_rcp(1.0f + __expf(-x));
}
__device__ __forceinline__ float tanh_fast(float x) {
  return 2.0f * fast_rcp(1.0f + __expf(-2.0f * x)) - 1.0f;
}
__device__ __forceinline__ float fdot2f(h2_t a, h2_t b, float c) {
#if __has_builtin(__builtin_amdgcn_fdot2)
  return __builtin_amdgcn_fdot2(a, b, c, false);
#else
  return c + (float)a.x * (float)b.x + (float)a.y * (float)b.y;
#endif
}
__device__ __forceinline__ unsigned short f2bf(float v) {
  return __builtin_bit_cast(unsigned short, __float2bfloat16(v));
}

__global__ void k_msg(const float* __restrict__ x, const int* __restrict__ ei,
                      const float* __restrict__ ea, const float* __restrict__ mw,
                      const float* __restrict__ mb, float* __restrict__ aggr) {
  __shared__ float wT[DN + DE][DM];
  __shared__ float bl[DM];
  for (int i = threadIdx.x; i < (DN + DE) * DM; i += 256) {
    int k = i >> 6, o = i & 63;
    wT[k][o] = mw[o * (DN + DE) + k];
  }
  if (threadIdx.x < DM) bl[threadIdx.x] = mb[threadIdx.x];
  __syncthreads();
  int e = blockIdx.x * 256 + threadIdx.x;
  if (e >= NE) return;
  int src = ei[e];
  int dst = ei[NE + e];
  float acc[DM];
#pragma unroll
  for (int o = 0; o < DM; ++o) acc[o] = bl[o];
  const float* xr = x + (size_t)src * DN;
  for (int k = 0; k < DN; ++k) {
    float f = xr[k];
#pragma unroll
    for (int o = 0; o < DM; ++o) acc[o] += f * wT[k][o];
  }
  const float* er = ea + (size_t)e * DE;
  for (int k = 0; k < DE; ++k) {
    float f = er[k];
#pragma unroll
    for (int o = 0; o < DM; ++o) acc[o] += f * wT[DN + k][o];
  }
  float* ar = aggr + (size_t)dst * DM;
#pragma unroll
  for (int o = 0; o < DM; ++o) atomicAdd(&ar[o], acc[o]);
}

__global__ void k_update(const float* __restrict__ x, const float* __restrict__ aggr,
                         const float* __restrict__ uw, const float* __restrict__ ub,
                         float* __restrict__ h) {
  __shared__ float l[16][DN + DM];
  int r0 = blockIdx.x * 16;
  for (int i = threadIdx.x; i < 16 * (DN + DM); i += 128) {
    int r = i / (DN + DM), k = i % (DN + DM);
    l[r][k] = (k < DN) ? x[(size_t)(r0 + r) * DN + k]
                       : aggr[(size_t)(r0 + r) * DM + (k - DN)];
  }
  __syncthreads();
  int o = threadIdx.x;
  float b = ub[o];
  float acc[16];
#pragma unroll
  for (int r = 0; r < 16; ++r) acc[r] = b;
  const float* wr = uw + (size_t)o * (DN + DM);
  for (int k = 0; k < DN + DM; ++k) {
    float wv = wr[k];
#pragma unroll
    for (int r = 0; r < 16; ++r) acc[r] += wv * l[r][k];
  }
#pragma unroll
  for (int r = 0; r < 16; ++r) h[(size_t)(r0 + r) * DN + o] = acc[r];
}

__global__ void k_gates(const float* __restrict__ h,
                        const float* __restrict__ wf, const float* __restrict__ wrv,
                        const float* __restrict__ bif, const float* __restrict__ bhf,
                        const float* __restrict__ bir, const float* __restrict__ bhr,
                        float* __restrict__ gf, float* __restrict__ gr) {
  __shared__ float l1[16][DN];
  __shared__ float l2[16][DN];
  int t0 = blockIdx.x * 16;
  for (int i = threadIdx.x; i < 16 * DN; i += 256) {
    int r = i >> 7, k = i & 127;
    l1[r][k] = h[(size_t)(t0 + r) * DN + k];
    l2[r][k] = h[(size_t)(NN - 1 - (t0 + r)) * DN + k];
  }
  __syncthreads();
  int tid = threadIdx.x;
  float acc[8][16];
#pragma unroll
  for (int i = 0; i < 8; ++i)
#pragma unroll
    for (int r = 0; r < 16; ++r) acc[i][r] = 0.f;
  for (int k = 0; k < DN; ++k) {
    float v1[16], v2[16];
#pragma unroll
    for (int r = 0; r < 16; ++r) { v1[r] = l1[r][k]; v2[r] = l2[r][k]; }
#pragma unroll
    for (int i = 0; i < 8; ++i) {
      int out = tid + (i & 3) * 256;
      float wv = (i < 4) ? wf[(size_t)out * DN + k] : wrv[(size_t)out * DN + k];
      if (i < 4) {
#pragma unroll
        for (int r = 0; r < 16; ++r) acc[i][r] += wv * v1[r];
      } else {
#pragma unroll
        for (int r = 0; r < 16; ++r) acc[i][r] += wv * v2[r];
      }
    }
  }
#pragma unroll
  for (int i = 0; i < 8; ++i) {
    int out = tid + (i & 3) * 256;
    float b = (i < 4) ? (bif[out] + bhf[out]) : (bir[out] + bhr[out]);
#pragma unroll
    for (int r = 0; r < 16; ++r) {
      if (i < 4) gf[(size_t)(t0 + r) * 1024 + out] = acc[i][r] + b;
      else       gr[(size_t)(t0 + r) * 1024 + out] = acc[i][r] + b;
    }
  }
}

__global__ __launch_bounds__(256, 1) void k_lstm(
    const float* __restrict__ whh_f, const float* __restrict__ whh_r,
    const float* __restrict__ gf, const float* __restrict__ gr,
    unsigned long long* __restrict__ hg, float* __restrict__ lstm_out) {
  int bid = blockIdx.x;
  if ((bid & 7) != 0) return;
  int idx = bid >> 3;
  if (idx >= 8) return;
  int dir = idx >> 2;
  int part = idx & 3;
  int tid = threadIdx.x;
  int gate = tid >> 6;
  int j = tid & 63;
  int hidx = part * 64 + j;
  int grow = gate * 256 + hidx;
  const float* whh = dir ? whh_r : whh_f;
  const float* gates = dir ? gr : gf;
  __shared__ unsigned int h2buf[128];
  __shared__ float glds[256];

  h2_t w2[128];
  const float4* wrow = (const float4*)(whh + (size_t)grow * HL);
#pragma unroll
  for (int k4 = 0; k4 < 64; ++k4) {
    float4 wv = wrow[k4];
    h2_t p0; p0.x = (_Float16)wv.x; p0.y = (_Float16)wv.y;
    h2_t p1; p1.x = (_Float16)wv.z; p1.y = (_Float16)wv.w;
    w2[2 * k4] = p0;
    w2[2 * k4 + 1] = p1;
  }
  if (tid < 128) h2buf[tid] = 0u;
  __syncthreads();

  float c = 0.f;
  float gcur = gates[grow];
  unsigned long long* hgd = hg + (size_t)dir * NN * 128;

  for (int t = 0; t < NN; ++t) {
    float gnext = gates[(size_t)(t + 1) * 1024 + grow];
    float a0 = gcur, a1 = 0.f, a2 = 0.f, a3 = 0.f;
    const uint4* hb = (const uint4*)h2buf;
#pragma unroll
    for (int k4 = 0; k4 < 32; ++k4) {
      uint4 hv = hb[k4];
      a0 = fdot2f(w2[4 * k4 + 0], __builtin_bit_cast(h2_t, hv.x), a0);
      a1 = fdot2f(w2[4 * k4 + 1], __builtin_bit_cast(h2_t, hv.y), a1);
      a2 = fdot2f(w2[4 * k4 + 2], __builtin_bit_cast(h2_t, hv.z), a2);
      a3 = fdot2f(w2[4 * k4 + 3], __builtin_bit_cast(h2_t, hv.w), a3);
    }
    float acc = (a0 + a1) + (a2 + a3);
    float av = (gate == 2) ? tanh_fast(acc) : sigf(acc);
    glds[gate * 64 + j] = av;
    __syncthreads();
    if (gate == 0) {
      float fi = glds[j];
      float ff = glds[64 + j];
      float fg = glds[128 + j];
      float fo = glds[192 + j];
      c = ff * c + fi * fg;
      float hval = fo * tanh_fast(c);
      int n = dir ? (NN - 1 - t) : t;
      lstm_out[(size_t)n * DA + dir * HL + hidx] = hval;
      _Float16 h16 = (_Float16)hval;
      ((_Float16*)h2buf)[hidx] = h16;
      unsigned int ub = (unsigned int)__builtin_bit_cast(unsigned short, h16);
      unsigned int other = __shfl_xor(ub, 1);
      if ((j & 1) == 0) {
        unsigned long long val =
            (unsigned long long)(ub | (other << 16)) |
            ((unsigned long long)(unsigned int)(t + 1) << 32);
        __hip_atomic_store(&hgd[(size_t)t * 128 + part * 32 + (j >> 1)], val,
                           __ATOMIC_RELAXED, __HIP_MEMORY_SCOPE_AGENT);
      }
    } else {
      int peer = (part + gate) & 3;
      if (j < 32) {
        size_t slot = (size_t)t * 128 + peer * 32 + j;
        unsigned int tag = (unsigned int)(t + 1);
        unsigned long long v;
        do {
          v = __hip_atomic_load(&hgd[slot], __ATOMIC_RELAXED,
                                __HIP_MEMORY_SCOPE_AGENT);
        } while ((unsigned int)(v >> 32) != tag);
        h2buf[peer * 32 + j] = (unsigned int)v;
      }
    }
    __syncthreads();
    gcur = gnext;
  }
}

__global__ void k_cast(const float* __restrict__ in, unsigned short* __restrict__ out, int n) {
  int stride = gridDim.x * 256;
  for (int i = blockIdx.x * 256 + threadIdx.x; i < n; i += stride)
    out[i] = f2bf(in[i]);
}

__global__ void k_effw(const float* __restrict__ opw, const float* __restrict__ fcw,
                       float* __restrict__ effw) {
  int k = blockIdx.x * 256 + threadIdx.x;
  if (k >= DA) return;
  float s = 0.f;
  for (int d = 0; d < DA; ++d) s += fcw[d] * opw[(size_t)d * DA + k];
  effw[k] = s;
}
__global__ void k_scalars(const float* __restrict__ opb, const float* __restrict__ fcw,
                          const float* __restrict__ fcb, const float* __restrict__ ipb,
                          const float* __restrict__ effw, float* __restrict__ scal) {
  __shared__ float red[512];
  int t = threadIdx.x;
  red[t] = fcw[t] * opb[t];
  __syncthreads();
  for (int s = 256; s > 0; s >>= 1) {
    if (t < s) red[t] += red[t + s];
    __syncthreads();
  }
  if (t == 0) scal[0] = red[0] + fcb[0];
  __syncthreads();
  red[t] = ipb[2 * DA + t] * effw[t];
  __syncthreads();
  for (int s = 256; s > 0; s >>= 1) {
    if (t < s) red[t] += red[t + s];
    __syncthreads();
  }
  if (t == 0) scal[1] = red[0];
}
__global__ void k_wveff(const float* __restrict__ ipw, const float* __restrict__ effw,
                        float* __restrict__ wveff) {
  int jc = blockIdx.x * 256 + threadIdx.x;
  if (jc >= DA) return;
  float s = 0.f;
  for (int k = 0; k < DA; ++k) s += effw[k] * ipw[(size_t)(2 * DA + k) * DA + jc];
  wveff[jc] = s;
}
__global__ void k_veff(const float* __restrict__ lstm, const float* __restrict__ wveff,
                       const float* __restrict__ scal, float* __restrict__ veff) {
  int row = blockIdx.x * 4 + (threadIdx.x >> 6);
  int lane = threadIdx.x & 63;
  const float4* a = (const float4*)(lstm + (size_t)row * DA + lane * 8);
  const float4* w = (const float4*)(wveff + lane * 8);
  float4 x0 = a[0], x1 = a[1], w0 = w[0], w1 = w[1];
  float s = x0.x * w0.x + x0.y * w0.y + x0.z * w0.z + x0.w * w0.w +
            x1.x * w1.x + x1.y * w1.y + x1.z * w1.z + x1.w * w1.w;
#pragma unroll
  for (int off = 1; off < 64; off <<= 1) s += __shfl_xor(s, off);
  if (lane == 0) veff[row] = s + scal[1];
}

__global__ void k_inproj(const unsigned short* __restrict__ lstm_bf,
                         const unsigned short* __restrict__ w_bf,
                         const float* __restrict__ ipb,
                         unsigned short* __restrict__ q_bf,
                         unsigned short* __restrict__ k_bf) {
  int rt = blockIdx.x >> 2;
  int cg = blockIdx.x & 3;
  int w = threadIdx.x >> 6;
  int lane = threadIdx.x & 63;
  int r0 = rt * 16;
  int rA = lane & 15;
  int kg = lane >> 4;
  short8 a[16];
#pragma unroll
  for (int kk = 0; kk < 16; ++kk)
    a[kk] = *(const short8*)(lstm_bf + (size_t)(r0 + rA) * DA + kk * 32 + kg * 8);
  const float rs = 0.04419417382415922f;
  for (int ct = 0; ct < 4; ++ct) {
    int col0 = cg * 256 + w * 64 + ct * 16;
    f32x4 acc = {0.f, 0.f, 0.f, 0.f};
#pragma unroll
    for (int kk = 0; kk < 16; ++kk) {
      short8 b = *(const short8*)(w_bf + (size_t)(col0 + rA) * DA + kk * 32 + kg * 8);
      acc = __builtin_amdgcn_mfma_f32_16x16x32_bf16(a[kk], b, acc, 0, 0, 0);
    }
    int col = col0 + rA;
    float bv = ipb[col];
#pragma unroll
    for (int i = 0; i < 4; ++i) {
      int rowo = r0 + kg * 4 + i;
      float v = acc[i] + bv;
      if (col < DA)
        q_bf[(size_t)rowo * DA + col] = f2bf(v * rs);
      else
        k_bf[(size_t)rowo * DA + (col - DA)] = f2bf(v);
    }
  }
}

__global__ __launch_bounds__(256) void k_attn(
    const unsigned short* __restrict__ q_bf, const unsigned short* __restrict__ k_bf,
    const float* __restrict__ veff, const float* __restrict__ scal,
    float* __restrict__ out) {
  __shared__ float zpart[4][32];
  __shared__ float fpart[4][32];
  __shared__ float invZ[32];
  int r0 = blockIdx.x * 32;
  int w = threadIdx.x >> 6;
  int lane = threadIdx.x & 63;
  int rA = lane & 15;
  int kg = lane >> 4;
  int cq = w * 2048;
  float* S = out + NN;

  short8 a0[16], a1[16];
#pragma unroll
  for (int kk = 0; kk < 16; ++kk) {
    a0[kk] = *(const short8*)(q_bf + (size_t)(r0 + rA) * DA + kk * 32 + kg * 8);
    a1[kk] = *(const short8*)(q_bf + (size_t)(r0 + 16 + rA) * DA + kk * 32 + kg * 8);
  }
  float zs[8], fs[8];
#pragma unroll
  for (int i = 0; i < 8; ++i) { zs[i] = 0.f; fs[i] = 0.f; }

  for (int ct = 0; ct < 128; ++ct) {
    int col0 = cq + ct * 16;
    f32x4 acc0 = {0.f, 0.f, 0.f, 0.f}, acc1 = {0.f, 0.f, 0.f, 0.f};
#pragma unroll
    for (int kk = 0; kk < 16; ++kk) {
      short8 b = *(const short8*)(k_bf + (size_t)(col0 + rA) * DA + kk * 32 + kg * 8);
      acc0 = __builtin_amdgcn_mfma_f32_16x16x32_bf16(a0[kk], b, acc0, 0, 0, 0);
      acc1 = __builtin_amdgcn_mfma_f32_16x16x32_bf16(a1[kk], b, acc1, 0, 0, 0);
    }
    int col = col0 + rA;
    float vv = veff[col];
#pragma unroll
    for (int i = 0; i < 4; ++i) {
      float e0 = __expf(fminf(acc0[i], 60.f));
      float e1 = __expf(fminf(acc1[i], 60.f));
      zs[i] += e0; zs[4 + i] += e1;
      fs[i] += e0 * vv; fs[4 + i] += e1 * vv;
      S[(size_t)(r0 + kg * 4 + i) * NN + col] = e0;
      S[(size_t)(r0 + 16 + kg * 4 + i) * NN + col] = e1;
    }
  }
#pragma unroll
  for (int i = 0; i < 8; ++i) {
#pragma unroll
    for (int off = 1; off < 16; off <<= 1) {
      zs[i] += __shfl_xor(zs[i], off);
      fs[i] += __shfl_xor(fs[i], off);
    }
  }
  if (rA == 0) {
#pragma unroll
    for (int i = 0; i < 4; ++i) {
      zpart[w][kg * 4 + i] = zs[i];
      zpart[w][16 + kg * 4 + i] = zs[4 + i];
      fpart[w][kg * 4 + i] = fs[i];
      fpart[w][16 + kg * 4 + i] = fs[4 + i];
    }
  }
  __syncthreads();
  if (threadIdx.x < 32) {
    int r = threadIdx.x;
    float Z = zpart[0][r] + zpart[1][r] + zpart[2][r] + zpart[3][r];
    float F = fpart[0][r] + fpart[1][r] + fpart[2][r] + fpart[3][r];
    float inv = 1.0f / Z;
    invZ[r] = inv;
    out[r0 + r] = F * inv + scal[0];
  }
  __syncthreads();
  for (int r = 0; r < 32; ++r) {
    float inv = invZ[r];
    float* row = S + (size_t)(r0 + r) * NN + cq;
#pragma unroll
    for (int it = 0; it < 8; ++it) {
      float4* p = (float4*)(row + it * 256 + lane * 4);
      float4 v = *p;
      v.x *= inv; v.y *= inv; v.z *= inv; v.w *= inv;
      *p = v;
    }
  }
}

extern "C" void kernel_launch(void* const* d_in, const int* in_sizes, int n_in,
                              void* d_out, int out_size, void* d_ws, size_t ws_size,
                              hipStream_t stream) {
  (void)in_sizes; (void)n_in; (void)out_size; (void)ws_size;
  const float* x    = (const float*)d_in[0];
  const int*   ei   = (const int*)d_in[1];
  const float* ea   = (const float*)d_in[2];
  const float* msw  = (const float*)d_in[3];
  const float* msb  = (const float*)d_in[4];
  const float* upw  = (const float*)d_in[5];
  const float* upb  = (const float*)d_in[6];
  const float* wihf = (const float*)d_in[7];
  const float* whhf = (const float*)d_in[8];
  const float* bihf = (const float*)d_in[9];
  const float* bhhf = (const float*)d_in[10];
  const float* wihr = (const float*)d_in[11];
  const float* whhr = (const float*)d_in[12];
  const float* bihr = (const float*)d_in[13];
  const float* bhhr = (const float*)d_in[14];
  const float* ipw  = (const float*)d_in[15];
  const float* ipb  = (const float*)d_in[16];
  const float* opw  = (const float*)d_in[17];
  const float* opb  = (const float*)d_in[18];
  const float* fcw  = (const float*)d_in[19];
  const float* fcb  = (const float*)d_in[20];
  float* out = (float*)d_out;

  char* ws = (char*)d_ws;
  size_t off = 0;
  auto alloc = [&](size_t bytes) {
    void* p = ws + off;
    off = (off + bytes + 255) & ~(size_t)255;
    return p;
  };
  float* aggr  = (float*)alloc((size_t)NN * DM * 4);
  float* hnode = (float*)alloc((size_t)NN * DN * 4);
  float* gf    = (float*)alloc((size_t)(NN + 1) * 1024 * 4);
  float* gr    = (float*)alloc((size_t)(NN + 1) * 1024 * 4);
  float* lstm  = (float*)alloc((size_t)NN * DA * 4);
  unsigned short* lstm_bf = (unsigned short*)alloc((size_t)NN * DA * 2);
  unsigned short* qbf     = (unsigned short*)alloc((size_t)NN * DA * 2);
  unsigned short* kbf     = (unsigned short*)alloc((size_t)NN * DA * 2);
  unsigned short* wbf     = (unsigned short*)alloc((size_t)1024 * DA * 2);
  unsigned long long* hg  = (unsigned long long*)alloc((size_t)2 * NN * 128 * 8);
  float* effw  = (float*)alloc(DA * 4);
  float* wveff = (float*)alloc(DA * 4);
  float* veff  = (float*)alloc(NN * 4);
  float* scal  = (float*)alloc(64 * 4);

  hipMemsetAsync(aggr, 0, (size_t)NN * DM * 4, stream);
  hipMemsetAsync(hg, 0, (size_t)2 * NN * 128 * 8, stream);

  k_msg<<<NE / 256, 256, 0, stream>>>(x, ei, ea, msw, msb, aggr);
  k_update<<<NN / 16, 128, 0, stream>>>(x, aggr, upw, upb, hnode);
  k_gates<<<NN / 16, 256, 0, stream>>>(hnode, wihf, wihr, bihf, bhhf, bihr, bhhr, gf, gr);
  k_lstm<<<64, 256, 0, stream>>>(whhf, whhr, gf, gr, hg, lstm);
  k_cast<<<2048, 256, 0, stream>>>(lstm, lstm_bf, NN * DA);
  k_cast<<<1024, 256, 0, stream>>>(ipw, wbf, 1024 * DA);
  k_effw<<<2, 256, 0, stream>>>(opw, fcw, effw);
  k_scalars<<<1, 512, 0, stream>>>(opb, fcw, fcb, ipb, effw, scal);
  k_wveff<<<2, 256, 0, stream>>>(ipw, effw, wveff);
  k_veff<<<NN / 4, 256, 0, stream>>>(lstm, wveff, scal, veff);
  k_inproj<<<2048, 256, 0, stream>>>(lstm_bf, wbf, ipb, qbf, kbf);
  k_attn<<<NN / 32, 256, 0, stream>>>(qbf, kbf, veff, scal, out);
}